// Round 1
// baseline (202.021 us; speedup 1.0000x reference)
//
#include <hip/hip_runtime.h>
#include <hip/hip_cooperative_groups.h>

namespace cg = cooperative_groups;

#define N_FEAT 128
#define NBLK   1024
#define NTHR   256
#define NSEG   ((NBLK * NTHR) / 32)   // 8192 32-lane segments per sweep

// Fused: phase 1 computes per-node projections p_src/p_trg (32 lanes/node,
// float4 loads, segment shuffle reduce), grid.sync, phase 2 gathers per edge.
// One launch instead of two — tests whether the 99µs-vs-15µs gap is
// launch/serialization overhead (H2) or harness re-poison floor (H1).
__global__ __launch_bounds__(NTHR, 4) void fused_kernel(
    const float* __restrict__ x, const float* __restrict__ W,
    const float* __restrict__ b,
    const int* __restrict__ esrc, const int* __restrict__ etrg,
    float* __restrict__ out, float* __restrict__ p_src, float* __restrict__ p_trg,
    int n_nodes, int n_edges4)
{
    const int tid = blockIdx.x * NTHR + threadIdx.x;
    const int sub = threadIdx.x & 31;   // lane within 32-lane segment
    const int seg = tid >> 5;           // segment id == starting node

    // ---- Phase 1: p_src[n] = x[n]·W[0,:128], p_trg[n] = x[n]·W[0,128:] ----
    const float4 wsv = *reinterpret_cast<const float4*>(W + 4 * sub);
    const float4 wtv = *reinterpret_cast<const float4*>(W + N_FEAT + 4 * sub);

    int node = seg;                      // seg < 8192 < n_nodes, always valid
    if (node < n_nodes) {
        float4 xv = *reinterpret_cast<const float4*>(x + (size_t)node * N_FEAT + 4 * sub);
        for (;;) {
            const int nxt = node + NSEG;
            const bool more = (nxt < n_nodes);
            float4 xn;
            if (more)                    // 1-deep prefetch: next x tile in flight
                xn = *reinterpret_cast<const float4*>(x + (size_t)nxt * N_FEAT + 4 * sub);

            float ssrc = fmaf(xv.x, wsv.x, fmaf(xv.y, wsv.y, fmaf(xv.z, wsv.z, xv.w * wsv.w)));
            float strg = fmaf(xv.x, wtv.x, fmaf(xv.y, wtv.y, fmaf(xv.z, wtv.z, xv.w * wtv.w)));
            #pragma unroll
            for (int off = 16; off > 0; off >>= 1) {
                ssrc += __shfl_down(ssrc, off, 32);   // width 32: stays in segment
                strg += __shfl_down(strg, off, 32);
            }
            if (sub == 0) {
                p_src[node] = ssrc;
                p_trg[node] = strg;
            }
            if (!more) break;
            node = nxt;
            xv = xn;
        }
    }

    cg::this_grid().sync();

    // ---- Phase 2: 4 edges per thread, gathers hit L2-resident p tables ----
    const float bias = b[0];
    for (int i = tid; i < n_edges4; i += NBLK * NTHR) {
        const int4 s = reinterpret_cast<const int4*>(esrc)[i];
        const int4 t = reinterpret_cast<const int4*>(etrg)[i];
        float4 o;
        o.x = 1.0f / (1.0f + __expf(-(p_src[s.x] + p_trg[t.x] + bias)));
        o.y = 1.0f / (1.0f + __expf(-(p_src[s.y] + p_trg[t.y] + bias)));
        o.z = 1.0f / (1.0f + __expf(-(p_src[s.z] + p_trg[t.z] + bias)));
        o.w = 1.0f / (1.0f + __expf(-(p_src[s.w] + p_trg[t.w] + bias)));
        reinterpret_cast<float4*>(out)[i] = o;
    }
}

// ---- Fallback path (proven 2-kernel version) in case cooperative launch
// ---- is rejected by the capture environment.
__global__ __launch_bounds__(256) void project_kernel(
    const float* __restrict__ x, const float* __restrict__ W,
    float* __restrict__ p_src, float* __restrict__ p_trg, int n_nodes)
{
    int gid  = blockIdx.x * blockDim.x + threadIdx.x;
    int node = gid >> 5;
    int sub  = threadIdx.x & 31;
    if (node >= n_nodes) return;

    const float4 xv = *reinterpret_cast<const float4*>(x + (size_t)node * N_FEAT + 4 * sub);
    const float4 ws = *reinterpret_cast<const float4*>(W + 4 * sub);
    const float4 wt = *reinterpret_cast<const float4*>(W + N_FEAT + 4 * sub);

    float ssrc = fmaf(xv.x, ws.x, fmaf(xv.y, ws.y, fmaf(xv.z, ws.z, xv.w * ws.w)));
    float strg = fmaf(xv.x, wt.x, fmaf(xv.y, wt.y, fmaf(xv.z, wt.z, xv.w * wt.w)));

    #pragma unroll
    for (int off = 16; off > 0; off >>= 1) {
        ssrc += __shfl_down(ssrc, off, 32);
        strg += __shfl_down(strg, off, 32);
    }
    if (sub == 0) {
        p_src[node] = ssrc;
        p_trg[node] = strg;
    }
}

__global__ __launch_bounds__(256) void edge_kernel(
    const int* __restrict__ esrc, const int* __restrict__ etrg,
    const float* __restrict__ p_src, const float* __restrict__ p_trg,
    const float* __restrict__ b, float* __restrict__ out, int n_edges4)
{
    int i = blockIdx.x * blockDim.x + threadIdx.x;
    if (i >= n_edges4) return;
    const int4 s = reinterpret_cast<const int4*>(esrc)[i];
    const int4 t = reinterpret_cast<const int4*>(etrg)[i];
    const float bias = b[0];

    float4 o;
    o.x = 1.0f / (1.0f + __expf(-(p_src[s.x] + p_trg[t.x] + bias)));
    o.y = 1.0f / (1.0f + __expf(-(p_src[s.y] + p_trg[t.y] + bias)));
    o.z = 1.0f / (1.0f + __expf(-(p_src[s.z] + p_trg[t.z] + bias)));
    o.w = 1.0f / (1.0f + __expf(-(p_src[s.w] + p_trg[t.w] + bias)));
    reinterpret_cast<float4*>(out)[i] = o;
}

extern "C" void kernel_launch(void* const* d_in, const int* in_sizes, int n_in,
                              void* d_out, int out_size, void* d_ws, size_t ws_size,
                              hipStream_t stream)
{
    // setup_inputs() dict order: input, edge_src_nodes, edge_trg_nodes, W, b
    const float* x    = (const float*)d_in[0];
    const int*   esrc = (const int*)d_in[1];
    const int*   etrg = (const int*)d_in[2];
    const float* W    = (const float*)d_in[3];
    const float* b    = (const float*)d_in[4];
    float* out = (float*)d_out;

    int n_nodes  = in_sizes[0] / N_FEAT;   // 100000
    int n_edges  = in_sizes[1];            // 640000
    int n_edges4 = n_edges / 4;            // 160000

    float* p_src = (float*)d_ws;           // n_nodes floats
    float* p_trg = p_src + n_nodes;        // n_nodes floats

    void* args[] = { (void*)&x, (void*)&W, (void*)&b, (void*)&esrc, (void*)&etrg,
                     (void*)&out, (void*)&p_src, (void*)&p_trg,
                     (void*)&n_nodes, (void*)&n_edges4 };
    hipError_t err = hipLaunchCooperativeKernel((void*)fused_kernel,
                                                dim3(NBLK), dim3(NTHR),
                                                args, 0, stream);
    if (err != hipSuccess) {
        // Fallback: proven two-kernel path.
        const int threads = 256;
        int blocks1 = (n_nodes * 32 + threads - 1) / threads;
        project_kernel<<<blocks1, threads, 0, stream>>>(x, W, p_src, p_trg, n_nodes);
        int blocks2 = (n_edges4 + threads - 1) / threads;
        edge_kernel<<<blocks2, threads, 0, stream>>>(esrc, etrg, p_src, p_trg, b, out, n_edges4);
    }
}

// Round 2
// 99.879 us; speedup vs baseline: 2.0227x; 2.0227x over previous
//
#include <hip/hip_runtime.h>

#define N_FEAT 128

// Pass 1: per-node projection, p_src[n] = x[n]·W[0,:128], p_trg[n] = x[n]·W[0,128:].
// 32 lanes per node, float4 (16 B) loads per lane — a 64-lane wave covers 2
// consecutive nodes = 1024 B contiguous, perfectly coalesced. Reduction is 5
// shfl steps confined to 32-lane segments. Memory-bound: 51.2 MB read of x
// at ~6.3 TB/s achievable => ~8 µs floor.
__global__ __launch_bounds__(256) void project_kernel(
    const float* __restrict__ x, const float* __restrict__ W,
    float* __restrict__ p_src, float* __restrict__ p_trg, int n_nodes)
{
    int gid  = blockIdx.x * blockDim.x + threadIdx.x;
    int node = gid >> 5;           // 32 lanes per node
    int sub  = threadIdx.x & 31;   // lane within the 32-lane segment
    if (node >= n_nodes) return;

    const float4 xv = *reinterpret_cast<const float4*>(x + (size_t)node * N_FEAT + 4 * sub);
    const float4 ws = *reinterpret_cast<const float4*>(W + 4 * sub);            // W_src slice
    const float4 wt = *reinterpret_cast<const float4*>(W + N_FEAT + 4 * sub);   // W_trg slice

    float ssrc = fmaf(xv.x, ws.x, fmaf(xv.y, ws.y, fmaf(xv.z, ws.z, xv.w * ws.w)));
    float strg = fmaf(xv.x, wt.x, fmaf(xv.y, wt.y, fmaf(xv.z, wt.z, xv.w * wt.w)));

    #pragma unroll
    for (int off = 16; off > 0; off >>= 1) {
        ssrc += __shfl_down(ssrc, off, 32);   // width 32: stays within the segment
        strg += __shfl_down(strg, off, 32);
    }
    if (sub == 0) {
        p_src[node] = ssrc;
        p_trg[node] = strg;
    }
}

// Pass 2: 4 edges per thread. int4 index loads, scalar gathers against the
// two 400 KB projection tables (L2/L3-resident), float4 output store.
__global__ __launch_bounds__(256) void edge_kernel(
    const int* __restrict__ esrc, const int* __restrict__ etrg,
    const float* __restrict__ p_src, const float* __restrict__ p_trg,
    const float* __restrict__ b, float* __restrict__ out, int n_edges4)
{
    int i = blockIdx.x * blockDim.x + threadIdx.x;
    if (i >= n_edges4) return;
    const int4 s = reinterpret_cast<const int4*>(esrc)[i];
    const int4 t = reinterpret_cast<const int4*>(etrg)[i];
    const float bias = b[0];

    float4 o;
    o.x = 1.0f / (1.0f + __expf(-(p_src[s.x] + p_trg[t.x] + bias)));
    o.y = 1.0f / (1.0f + __expf(-(p_src[s.y] + p_trg[t.y] + bias)));
    o.z = 1.0f / (1.0f + __expf(-(p_src[s.z] + p_trg[t.z] + bias)));
    o.w = 1.0f / (1.0f + __expf(-(p_src[s.w] + p_trg[t.w] + bias)));
    reinterpret_cast<float4*>(out)[i] = o;
}

extern "C" void kernel_launch(void* const* d_in, const int* in_sizes, int n_in,
                              void* d_out, int out_size, void* d_ws, size_t ws_size,
                              hipStream_t stream)
{
    // setup_inputs() dict order: input, edge_src_nodes, edge_trg_nodes, W, b
    const float* x    = (const float*)d_in[0];
    const int*   esrc = (const int*)d_in[1];
    const int*   etrg = (const int*)d_in[2];
    const float* W    = (const float*)d_in[3];
    const float* b    = (const float*)d_in[4];
    float* out = (float*)d_out;

    int n_nodes = in_sizes[0] / N_FEAT;   // 100000
    int n_edges = in_sizes[1];            // 640000 (divisible by 4)

    float* p_src = (float*)d_ws;          // n_nodes floats
    float* p_trg = p_src + n_nodes;       // n_nodes floats

    const int threads = 256;
    // 32 lanes per node -> 8 nodes per 256-thread block
    int blocks1 = (n_nodes * 32 + threads - 1) / threads;
    project_kernel<<<blocks1, threads, 0, stream>>>(x, W, p_src, p_trg, n_nodes);

    int n_edges4 = n_edges / 4;           // 160000
    int blocks2 = (n_edges4 + threads - 1) / threads;
    edge_kernel<<<blocks2, threads, 0, stream>>>(esrc, etrg, p_src, p_trg, b, out, n_edges4);
}